// Round 17
// baseline (199.648 us; speedup 1.0000x reference)
//
#include <hip/hip_runtime.h>
#include <hip/hip_fp16.h>
#include <stdint.h>

#define NF 64
#define WSHIFT 14          // src window = 16384 nodes (~2MB fp16) -> w in 0..6 for n=100K
#define NSEG 8             // 8 segments x 8 slots = 64 ELL slots
#define SEGSZ 8

#if defined(__has_builtin)
#  if __has_builtin(__builtin_amdgcn_fdot2)
#    define HAS_FDOT2 1
#  endif
#endif

typedef _Float16 half2v __attribute__((ext_vector_type(2)));
union H2 { int i; half2v v; __half2 h; };

__device__ __forceinline__ float dot2acc(half2v a, half2v b, float c) {
#ifdef HAS_FDOT2
    return __builtin_amdgcn_fdot2(a, b, c, false);
#else
    H2 ua; ua.v = a; H2 ub; ub.v = b;
    float2 fa = __half22float2(ua.h);
    float2 fb = __half22float2(ub.h);
    c = fmaf(fa.x, fb.x, c);
    return fmaf(fa.y, fb.y, c);
#endif
}

// ---------------- fill ELL (in d_out) with sentinel n ----------------
__global__ __launch_bounds__(256) void k_fill(int* ell, int n) {
    int4 s4;
    s4.x = s4.y = s4.z = s4.w = n;
    long total = (long)n * NF / 4;     // int4 count
    for (long i = (long)blockIdx.x * 256 + threadIdx.x; i < total; i += (long)gridDim.x * 256)
        reinterpret_cast<int4*>(ell)[i] = s4;
}

// ---------------- ELL build: segment by src-window; XCD dst-windowed ----------------
__global__ __launch_bounds__(256) void k_ell(const int* __restrict__ src,
                                             const int* __restrict__ dst,
                                             int* cnt8, int* ocnt, int* oflow, int ocap,
                                             int* ell, int e, int n) {
    int grp = blockIdx.x & 7;
    int chunk = (n + 7) >> 3;
    int lo = grp * chunk;
    int hi = min(lo + chunk, n);
    int nb = gridDim.x >> 3;
    int bi = blockIdx.x >> 3;
    for (int i = bi * 256 + threadIdx.x; i < e; i += nb * 256) {
        int d = dst[i];
        if (d < lo || d >= hi) continue;
        int s = src[i];
        int w = min(s >> WSHIFT, NSEG - 1);
        int slot = atomicAdd(&cnt8[(d << 3) + w], 1);
        if (slot < SEGSZ) {
            ell[(unsigned)d * NF + (w << 3) + slot] = s;
        } else {                                   // ~100 edges expected; exact fallback
            int o = atomicAdd(ocnt, 1);
            if (o < ocap) { oflow[2 * o] = s; oflow[2 * o + 1] = d; }
        }
    }
}

// ---------------- dinv from cnt8 (raw counts = true degree, uncapped) ----------------
__global__ __launch_bounds__(256) void k_dinv(const int* __restrict__ cnt8,
                                              float* __restrict__ dinv, int n) {
    int i = blockIdx.x * 256 + threadIdx.x;
    if (i >= n) return;
    int4 c0 = reinterpret_cast<const int4*>(cnt8)[i * 2];
    int4 c1 = reinterpret_cast<const int4*>(cnt8)[i * 2 + 1];
    int deg = c0.x + c0.y + c0.z + c0.w + c1.x + c1.y + c1.z + c1.w;
    dinv[i] = rsqrtf((float)(deg + 1));          // +1 self-loop
}

// ---------------- prescale to fp16: xh[row] = half(x[row]*dinv[row]); row n = 0 ----------------
__global__ __launch_bounds__(256) void k_scale(const float* __restrict__ x,
                                               const float* __restrict__ dinv,
                                               __half* __restrict__ xh, int n) {
    int i = blockIdx.x * 256 + threadIdx.x;      // 4-half chunk index (16 per row)
    int total = (n + 1) * (NF / 4);
    if (i >= total) return;
    int row = i >> 4;
    uint2 u = {0u, 0u};
    if (row < n) {
        float dd = dinv[row];
        float4 v = reinterpret_cast<const float4*>(x)[i];
        __half2 p0 = __floats2half2_rn(v.x * dd, v.y * dd);
        __half2 p1 = __floats2half2_rn(v.z * dd, v.w * dd);
        u.x = *reinterpret_cast<unsigned*>(&p0);
        u.y = *reinterpret_cast<unsigned*>(&p1);
    }
    reinterpret_cast<uint2*>(xh)[i] = u;         // row n -> zero row
}

// ---------------- fused window-phased gather + register-GEMM epilogue ----------------
// 1 node/wave. Segment j's srcs all lie in window j (~2MB) -> chip-wide phase
// alignment keeps the active window L2-resident. Sentinel-prefilled ELL ->
// mask-free. 8-lane groups x uint4: one wave-load per segment (8 edges).
// Epilogue: zero-LDS register dot2 (R15). No __shared__, no barriers.

__global__ __launch_bounds__(256) void k_agg_gemm(const __half* __restrict__ xh,
                                                  const float* __restrict__ W,
                                                  const float* __restrict__ bias,
                                                  const float* __restrict__ dinv,
                                                  float* out, int n) {
    unsigned lane = threadIdx.x & 63;
    int wv = threadIdx.x >> 6;
    unsigned grp = lane >> 3;          // 0..7: edge within segment
    unsigned fl  = lane & 7;           // feature octet: feats fl*8..fl*8+7
    float bj = bias[lane];

    // stage lane's W row into 32 packed half2 registers
    half2v w[32];
    {
        const float4* Wr = reinterpret_cast<const float4*>(W + (unsigned)lane * NF);
#pragma unroll
        for (int c = 0; c < 16; ++c) {
            float4 f = Wr[c];
            H2 u0; u0.h = __floats2half2_rn(f.x, f.y); w[2 * c] = u0.v;
            H2 u1; u1.h = __floats2half2_rn(f.z, f.w); w[2 * c + 1] = u1.v;
        }
    }

    const int* outi = (const int*)out;   // ELL aliased in out
    int ngroups = (n + 3) >> 2, gs = gridDim.x;
    int g = blockIdx.x;
    int d = g * 4 + wv;
    int ev = 0; float dd = 0.f;
    if (d < n) {
        ev = outi[(unsigned)d * NF + lane];    // full-wave 256B ELL row
        dd = dinv[d];
    }
    while (g < ngroups) {
        int gn = g + gs, dn = gn * 4 + wv;
        int evn = 0; float ddn = 0.f;
        if (gn < ngroups && dn < n) {          // prefetch next iteration
            evn = outi[(unsigned)dn * NF + lane];
            ddn = dinv[dn];
        }
        if (d < n) {
            float a0 = 0.f, a1 = 0.f, a2 = 0.f, a3 = 0.f;
            float a4 = 0.f, a5 = 0.f, a6 = 0.f, a7 = 0.f;
#pragma unroll
            for (int seg = 0; seg < NSEG; ++seg) {     // window-phase order
                int s = __shfl(ev, (seg << 3) + (int)grp);
                if (__all(s == n)) continue;           // empty segment
                uint4 u = *reinterpret_cast<const uint4*>(xh + (unsigned)s * NF + fl * 8);
                float2 f;
                f = __half22float2(*reinterpret_cast<const __half2*>(&u.x)); a0 += f.x; a1 += f.y;
                f = __half22float2(*reinterpret_cast<const __half2*>(&u.y)); a2 += f.x; a3 += f.y;
                f = __half22float2(*reinterpret_cast<const __half2*>(&u.z)); a4 += f.x; a5 += f.y;
                f = __half22float2(*reinterpret_cast<const __half2*>(&u.w)); a6 += f.x; a7 += f.y;
            }
            // combine the 8 edge-groups: butterfly over lane bits 3,4,5
#pragma unroll
            for (int mask = 8; mask <= 32; mask <<= 1) {
                a0 += __shfl_xor(a0, mask); a1 += __shfl_xor(a1, mask);
                a2 += __shfl_xor(a2, mask); a3 += __shfl_xor(a3, mask);
                a4 += __shfl_xor(a4, mask); a5 += __shfl_xor(a5, mask);
                a6 += __shfl_xor(a6, mask); a7 += __shfl_xor(a7, mask);
            }
            // self term (prescaled row d) + scale; lane holds v[fl*8..fl*8+7]
            uint4 us = *reinterpret_cast<const uint4*>(xh + (unsigned)d * NF + fl * 8);
            float2 f0 = __half22float2(*reinterpret_cast<const __half2*>(&us.x));
            float2 f1 = __half22float2(*reinterpret_cast<const __half2*>(&us.y));
            float2 f2 = __half22float2(*reinterpret_cast<const __half2*>(&us.z));
            float2 f3 = __half22float2(*reinterpret_cast<const __half2*>(&us.w));
            H2 hv0, hv1, hv2, hv3;
            hv0.h = __floats2half2_rn(dd * (a0 + f0.x), dd * (a1 + f0.y));
            hv1.h = __floats2half2_rn(dd * (a2 + f1.x), dd * (a3 + f1.y));
            hv2.h = __floats2half2_rn(dd * (a4 + f2.x), dd * (a5 + f2.y));
            hv3.h = __floats2half2_rn(dd * (a6 + f3.x), dd * (a7 + f3.y));
            int iv0 = hv0.i, iv1 = hv1.i, iv2 = hv2.i, iv3 = hv3.i;
            // register GEMM: v chunk pair (8f+2q, 8f+2q+1) lives in ivq of lane f (0..7)
            float r = bj;
            H2 p;
#pragma unroll
            for (int f = 0; f < 8; ++f) {
                p.i = __shfl(iv0, f); r = dot2acc(p.v, w[4 * f + 0], r);
                p.i = __shfl(iv1, f); r = dot2acc(p.v, w[4 * f + 1], r);
                p.i = __shfl(iv2, f); r = dot2acc(p.v, w[4 * f + 2], r);
                p.i = __shfl(iv3, f); r = dot2acc(p.v, w[4 * f + 3], r);
            }
            out[(unsigned)d * NF + lane] = r;
        }
        g = gn; d = dn; ev = evn; dd = ddn;
    }
}

// ---------------- overflow fixup (post-GEMM, by linearity; exact fp32 path) ----------------
__global__ __launch_bounds__(64) void k_oflow(const float* __restrict__ x,
                                              const float* __restrict__ W,
                                              const float* __restrict__ dinv,
                                              const int* __restrict__ ocnt,
                                              const int* __restrict__ oflow, int ocap,
                                              float* out) {
    int c = *ocnt; if (c > ocap) c = ocap;
    int lane = threadIdx.x;
    for (int o = blockIdx.x; o < c; o += gridDim.x) {
        int s = oflow[2 * o], d = oflow[2 * o + 1];
        float norm = dinv[s] * dinv[d];
        float r = 0.f;
        for (int k = 0; k < NF; ++k)
            r = fmaf(x[(long)s * NF + k], W[lane * NF + k], r);
        atomicAdd(&out[(long)d * NF + lane], norm * r);
    }
}

// ---------------- launch ----------------

extern "C" void kernel_launch(void* const* d_in, const int* in_sizes, int n_in,
                              void* d_out, int out_size, void* d_ws, size_t ws_size,
                              hipStream_t stream) {
    const float* x    = (const float*)d_in[0];
    const int*   ei   = (const int*)d_in[1];   // harness pushes integers as int32
    const float* W    = (const float*)d_in[2];
    const float* bias = (const float*)d_in[3];
    float*       out  = (float*)d_out;

    const int n = in_sizes[0] / NF;       // 100000
    const int e = in_sizes[1] / 2;        // 1250000
    const int* src = ei;
    const int* dst = ei + e;

    // ws layout: cnt8 n*8 ints | ocnt 1 | dinv n floats | align | xh (n+1)*64 halfs | oflow rest
    int*    cnt8 = (int*)d_ws;
    int*    ocnt = cnt8 + (size_t)n * 8;
    float*  dinv = (float*)(ocnt + 1);
    uintptr_t p = ((uintptr_t)(dinv + n) + 255) & ~(uintptr_t)255;
    __half* xh   = (__half*)p;
    int*    oflow = (int*)(xh + (size_t)(n + 1) * NF);
    long    rest = (long)ws_size - ((char*)oflow - (char*)d_ws);
    int     ocap = rest > 0 ? (int)(rest / 8) : 0;

    dim3 blk(256);
    (void)hipMemsetAsync(cnt8, 0, ((size_t)n * 8 + 1) * sizeof(int), stream);  // cnt8 + ocnt
    k_fill <<<2048, blk, 0, stream>>>((int*)out, n);
    k_ell  <<<2048, blk, 0, stream>>>(src, dst, cnt8, ocnt, oflow, ocap, (int*)out, e, n);
    k_dinv <<<(n + 255) / 256, blk, 0, stream>>>(cnt8, dinv, n);
    int total4 = (n + 1) * (NF / 4);
    k_scale<<<(total4 + 255) / 256, blk, 0, stream>>>(x, dinv, xh, n);
    k_agg_gemm<<<2048, blk, 0, stream>>>(xh, W, bias, dinv, out, n);
    k_oflow<<<64, 64, 0, stream>>>(x, W, dinv, ocnt, oflow, ocap, out);
}

// Round 18
// 145.975 us; speedup vs baseline: 1.3677x; 1.3677x over previous
//
#include <hip/hip_runtime.h>
#include <hip/hip_fp16.h>
#include <stdint.h>

#define NF 64

// ---------------- single-pass ELL build (ELL inside d_out), XCD-windowed ----------------
__global__ __launch_bounds__(256) void k_ell(const int* __restrict__ src,
                                             const int* __restrict__ dst,
                                             int* degc, int* ocnt, int* oflow, int ocap,
                                             int* ell, int e, int n) {
    int grp = blockIdx.x & 7;
    int chunk = (n + 7) >> 3;
    int lo = grp * chunk;
    int hi = min(lo + chunk, n);
    int nb = gridDim.x >> 3;
    int bi = blockIdx.x >> 3;
    for (int i = bi * 256 + threadIdx.x; i < e; i += nb * 256) {
        int d = dst[i];
        if (d < lo || d >= hi) continue;
        int s = src[i];
        int slot = atomicAdd(&degc[d], 1);
        if (slot < NF) {
            ell[(unsigned)d * NF + slot] = s;
        } else {                                   // P(deg>64)~0; correctness fallback
            int o = atomicAdd(ocnt, 1);
            if (o < ocap) { oflow[2 * o] = s; oflow[2 * o + 1] = d; }
        }
    }
}

// ---------------- prescale to fp16: xh[row] = half(x[row] * rsqrt(deg+1)); row n = 0 ----------------
__global__ __launch_bounds__(256) void k_scale(const float* __restrict__ x,
                                               const int* __restrict__ degc,
                                               __half* __restrict__ xh, int n) {
    int i = blockIdx.x * 256 + threadIdx.x;      // float4 index (16 per row)
    int total = (n + 1) * (NF / 4);
    if (i >= total) return;
    int row = i >> 4;
    uint2 u = {0u, 0u};
    if (row < n) {
        float dd = rsqrtf((float)(degc[row] + 1));
        float4 v = reinterpret_cast<const float4*>(x)[i];
        __half2 p0 = __floats2half2_rn(v.x * dd, v.y * dd);
        __half2 p1 = __floats2half2_rn(v.z * dd, v.w * dd);
        u.x = *reinterpret_cast<unsigned*>(&p0);
        u.y = *reinterpret_cast<unsigned*>(&p1);
    }
    reinterpret_cast<uint2*>(xh)[i] = u;         // row n -> zero row
}

// ---------------- fused gather-aggregate + GEMM epilogue ----------------
// 1 node/wave. Gather: 4 lane-groups x 16 lanes; group g takes edge j+g, lane
// loads uint2 (4 fp16 feats) -> ONE wave-load covers 4 edges' rows (4x fewer
// load instrs than lane-per-feature). f32 accumulation; groups combined via
// shfl_xor butterfly. No in-loop barriers.

__global__ __launch_bounds__(256) void k_agg_gemm(const __half* __restrict__ xh,
                                                  const float* __restrict__ W,
                                                  const float* __restrict__ bias,
                                                  const int* __restrict__ degc,
                                                  float* out, int n) {
    __shared__ float wt[NF * NF];      // wt[k*64+j] = W[j][k]
    __shared__ float vsh[4][NF];
    int tid = threadIdx.x;
    for (int idx = tid; idx < NF * NF; idx += 256) {
        int k = idx >> 6, j = idx & 63;
        wt[idx] = W[j * NF + k];
    }
    int wv = tid >> 6;
    unsigned lane = tid & 63;
    unsigned grp = lane >> 4;          // 0..3: which edge of the quad
    unsigned fl  = lane & 15;          // feature-quad index: feats fl*4..fl*4+3
    float bj = bias[lane];
    __syncthreads();                   // wt staged (only barrier)

    const int* outi = (const int*)out;   // ELL aliased in out
    int ngroups = (n + 3) >> 2, gs = gridDim.x;
    int g = blockIdx.x;
    int d = g * 4 + wv;
    int ev = 0, mc = 0;
    if (d < n) {
        ev = outi[(unsigned)d * NF + lane];    // full-wave 256B ELL row
        mc = degc[d];
    }
    while (g < ngroups) {
        int gn = g + gs, dn = gn * 4 + wv;
        int evn = 0, mcn = 0;
        if (gn < ngroups && dn < n) {          // prefetch next iteration
            evn = outi[(unsigned)dn * NF + lane];
            mcn = degc[dn];
        }
        if (d < n) {
            float dd = rsqrtf((float)(mc + 1));
            int m = min(mc, NF);
            float a0 = 0.f, a1 = 0.f, a2 = 0.f, a3 = 0.f;   // chain A feats
            float b0 = 0.f, b1 = 0.f, b2 = 0.f, b3 = 0.f;   // chain B feats
            float c0 = 0.f, c1 = 0.f, c2 = 0.f, c3 = 0.f;   // chain C
            float e0 = 0.f, e1 = 0.f, e2 = 0.f, e3 = 0.f;   // chain D
            for (int j = 0; j < m; j += 16) {  // 16 edges = 4 wave-loads in flight
                int i0 = j + (int)grp, i1 = j + 4 + (int)grp;
                int i2 = j + 8 + (int)grp, i3 = j + 12 + (int)grp;
                int s0 = __shfl(ev, i0); s0 = (i0 < m) ? s0 : n;
                int s1 = __shfl(ev, i1); s1 = (i1 < m) ? s1 : n;
                int s2 = __shfl(ev, i2); s2 = (i2 < m) ? s2 : n;
                int s3 = __shfl(ev, i3); s3 = (i3 < m) ? s3 : n;
                uint2 u0 = *reinterpret_cast<const uint2*>(xh + (unsigned)s0 * NF + fl * 4);
                uint2 u1 = *reinterpret_cast<const uint2*>(xh + (unsigned)s1 * NF + fl * 4);
                uint2 u2 = *reinterpret_cast<const uint2*>(xh + (unsigned)s2 * NF + fl * 4);
                uint2 u3 = *reinterpret_cast<const uint2*>(xh + (unsigned)s3 * NF + fl * 4);
                float2 f;
                f = __half22float2(*reinterpret_cast<const __half2*>(&u0.x)); a0 += f.x; a1 += f.y;
                f = __half22float2(*reinterpret_cast<const __half2*>(&u0.y)); a2 += f.x; a3 += f.y;
                f = __half22float2(*reinterpret_cast<const __half2*>(&u1.x)); b0 += f.x; b1 += f.y;
                f = __half22float2(*reinterpret_cast<const __half2*>(&u1.y)); b2 += f.x; b3 += f.y;
                f = __half22float2(*reinterpret_cast<const __half2*>(&u2.x)); c0 += f.x; c1 += f.y;
                f = __half22float2(*reinterpret_cast<const __half2*>(&u2.y)); c2 += f.x; c3 += f.y;
                f = __half22float2(*reinterpret_cast<const __half2*>(&u3.x)); e0 += f.x; e1 += f.y;
                f = __half22float2(*reinterpret_cast<const __half2*>(&u3.y)); e2 += f.x; e3 += f.y;
            }
            // self term (prescaled row d), loaded per lane-group (broadcast within group)
            uint2 us = *reinterpret_cast<const uint2*>(xh + (unsigned)d * NF + fl * 4);
            float2 fs0 = __half22float2(*reinterpret_cast<const __half2*>(&us.x));
            float2 fs1 = __half22float2(*reinterpret_cast<const __half2*>(&us.y));
            a0 = (a0 + b0) + (c0 + e0);
            a1 = (a1 + b1) + (c1 + e1);
            a2 = (a2 + b2) + (c2 + e2);
            a3 = (a3 + b3) + (c3 + e3);
            // combine the 4 edge-groups: butterfly over lanes {fl, fl+16, fl+32, fl+48}
            a0 += __shfl_xor(a0, 16); a1 += __shfl_xor(a1, 16);
            a2 += __shfl_xor(a2, 16); a3 += __shfl_xor(a3, 16);
            a0 += __shfl_xor(a0, 32); a1 += __shfl_xor(a1, 32);
            a2 += __shfl_xor(a2, 32); a3 += __shfl_xor(a3, 32);
            if (grp == 0) {                     // lanes 0..15 write v as float4
                float4 v4;
                v4.x = dd * (a0 + fs0.x);
                v4.y = dd * (a1 + fs0.y);
                v4.z = dd * (a2 + fs1.x);
                v4.w = dd * (a3 + fs1.y);
                *reinterpret_cast<float4*>(&vsh[wv][fl * 4]) = v4;   // wave-local
            }
            float r = bj;
#pragma unroll
            for (int k0 = 0; k0 < NF; k0 += 4) {
                float4 bv = *reinterpret_cast<const float4*>(&vsh[wv][k0]);  // broadcast
                r = fmaf(bv.x, wt[(k0 + 0) * NF + lane], r);
                r = fmaf(bv.y, wt[(k0 + 1) * NF + lane], r);
                r = fmaf(bv.z, wt[(k0 + 2) * NF + lane], r);
                r = fmaf(bv.w, wt[(k0 + 3) * NF + lane], r);
            }
            out[(unsigned)d * NF + lane] = r;
        }
        g = gn; d = dn; ev = evn; mc = mcn;
    }
}

// ---------------- overflow fixup (post-GEMM, by linearity; exact fp32 path) ----------------
__global__ __launch_bounds__(64) void k_oflow(const float* __restrict__ x,
                                              const float* __restrict__ W,
                                              const int* __restrict__ degc,
                                              const int* __restrict__ ocnt,
                                              const int* __restrict__ oflow, int ocap,
                                              float* out) {
    int c = *ocnt; if (c > ocap) c = ocap;
    int lane = threadIdx.x;
    for (int o = blockIdx.x; o < c; o += gridDim.x) {
        int s = oflow[2 * o], d = oflow[2 * o + 1];
        float norm = rsqrtf((float)(degc[s] + 1)) * rsqrtf((float)(degc[d] + 1));
        float r = 0.f;
        for (int k = 0; k < NF; ++k)
            r = fmaf(x[(long)s * NF + k], W[lane * NF + k], r);
        atomicAdd(&out[(long)d * NF + lane], norm * r);
    }
}

// ---------------- launch ----------------

extern "C" void kernel_launch(void* const* d_in, const int* in_sizes, int n_in,
                              void* d_out, int out_size, void* d_ws, size_t ws_size,
                              hipStream_t stream) {
    const float* x    = (const float*)d_in[0];
    const int*   ei   = (const int*)d_in[1];   // harness pushes integers as int32
    const float* W    = (const float*)d_in[2];
    const float* bias = (const float*)d_in[3];
    float*       out  = (float*)d_out;

    const int n = in_sizes[0] / NF;       // 100000
    const int e = in_sizes[1] / 2;        // 1250000
    const int* src = ei;
    const int* dst = ei + e;

    // ws layout: degc n | ocnt 1 | align | xh (n+1)*64 halfs | oflow rest
    int*    degc = (int*)d_ws;
    int*    ocnt = degc + n;
    uintptr_t p = ((uintptr_t)(ocnt + 1) + 255) & ~(uintptr_t)255;
    __half* xh   = (__half*)p;
    int*    oflow = (int*)(xh + (size_t)(n + 1) * NF);
    long    rest = (long)ws_size - ((char*)oflow - (char*)d_ws);
    int     ocap = rest > 0 ? (int)(rest / 8) : 0;

    dim3 blk(256);
    (void)hipMemsetAsync(degc, 0, (size_t)(n + 1) * sizeof(int), stream);  // degc + ocnt
    k_ell  <<<2048, blk, 0, stream>>>(src, dst, degc, ocnt, oflow, ocap, (int*)out, e, n);
    int total4 = (n + 1) * (NF / 4);
    k_scale<<<(total4 + 255) / 256, blk, 0, stream>>>(x, degc, xh, n);
    k_agg_gemm<<<2048, blk, 0, stream>>>(xh, W, bias, degc, out, n);
    k_oflow<<<64, 64, 0, stream>>>(x, W, degc, ocnt, oflow, ocap, out);
}